// Round 1
// baseline (189.800 us; speedup 1.0000x reference)
//
#include <hip/hip_runtime.h>
#include <stdint.h>

// Problem constants: B=16, K=8, F=512, INCH=512, OUTCH=512, R=8
// rows M = B*K*F = 65536; "bk" index = b*8+k (128 slices of 512 rows)

typedef __attribute__((ext_vector_type(8))) __bf16 bf16x8;
typedef __attribute__((ext_vector_type(4))) float f32x4;
typedef __attribute__((ext_vector_type(8))) unsigned short ushort8;
typedef __attribute__((ext_vector_type(4))) unsigned short ushort4_t;
typedef __attribute__((ext_vector_type(4))) float float4_t;

#define MFMA16(a, b, c) __builtin_amdgcn_mfma_f32_16x16x32_bf16((a), (b), (c), 0, 0, 0)
#define GLL16(g, l)                                                                   \
    __builtin_amdgcn_global_load_lds((const __attribute__((address_space(1))) void*)(g), \
                                     (__attribute__((address_space(3))) void*)(l), 16, 0, 0)

__device__ inline unsigned short f2bf(float f) {
    union { float fv; unsigned u; } un; un.fv = f;
    unsigned u = un.u;
    u += 0x7FFFu + ((u >> 16) & 1u);   // RNE
    return (unsigned short)(u >> 16);
}

__device__ inline float geluf(float x) {
    return 0.5f * x * (1.0f + erff(x * 0.70710678118654752f));
}

__device__ inline bf16x8 lds8(const unsigned short* p) {
    return __builtin_bit_cast(bf16x8, *(const ushort8*)p);
}

// ---------------- K0: fp32 -> bf16 weight convert (exact grid: n/1024 blocks) ---
__global__ void cvt_w(const float* __restrict__ w, unsigned short* __restrict__ o) {
    int i = blockIdx.x * 256 + threadIdx.x;
    float4_t v = *(const float4_t*)(w + (size_t)i * 4);
    ushort4_t r;
    r[0] = f2bf(v[0]); r[1] = f2bf(v[1]); r[2] = f2bf(v[2]); r[3] = f2bf(v[3]);
    *(ushort4_t*)(o + (size_t)i * 4) = r;
}

// ---------------- K1: mean over K (fp32) + x -> bf16.  grid 4096 x 256 ----------
__global__ void mean_cvt(const float* __restrict__ x,
                         unsigned short* __restrict__ xb,
                         unsigned short* __restrict__ xm) {
    int gid = blockIdx.x * 256 + threadIdx.x;   // B*F*128 = 1048576 threads
    int c  = gid & 127;          // float4 column
    int bf = gid >> 7;           // 0..8191
    int b  = bf >> 9;
    int f  = bf & 511;
    float4_t s = {0.f, 0.f, 0.f, 0.f};
#pragma unroll
    for (int k = 0; k < 8; ++k) {
        long row = (long)(b * 8 + k) * 512 + f;
        float4_t v = *(const float4_t*)(x + row * 512 + c * 4);
        s += v;
        ushort4_t t;
        t[0] = f2bf(v[0]); t[1] = f2bf(v[1]); t[2] = f2bf(v[2]); t[3] = f2bf(v[3]);
        *(ushort4_t*)(xb + row * 512 + c * 4) = t;
    }
    ushort4_t t;
    t[0] = f2bf(s[0] * 0.125f); t[1] = f2bf(s[1] * 0.125f);
    t[2] = f2bf(s[2] * 0.125f); t[3] = f2bf(s[3] * 0.125f);
    *(ushort4_t*)(xm + (long)bf * 512 + c * 4) = t;
}

// ---------------- K2/K3: O[M][Ntot] = gelu(A[M][512] @ W[N][512]^T + bias) bf16 --
// 128x128 tile, BK=32, 4 waves (2x2), m97 structure w/ global_load_lds width 16.
__launch_bounds__(256)
__global__ void gemm_gelu(const unsigned short* __restrict__ A,
                          const unsigned short* __restrict__ W,
                          const float* __restrict__ bias,
                          unsigned short* __restrict__ O,
                          int Ntot) {
    __shared__ __align__(16) unsigned short As[4096];  // [128 rows][32 k]
    __shared__ __align__(16) unsigned short Bs[4096];  // [128 cols][32 k]
    const int tid = threadIdx.x;
    const int w = tid >> 6, l = tid & 63;
    const int wr = w >> 1, wc = w & 1;
    const long row0 = (long)blockIdx.x * 128;
    const int  col0 = blockIdx.y * 128;

    f32x4 acc[4][4];
    const f32x4 z4 = {0.f, 0.f, 0.f, 0.f};
#pragma unroll
    for (int i = 0; i < 4; ++i)
#pragma unroll
        for (int j = 0; j < 4; ++j) acc[i][j] = z4;

    const int lrow = l >> 2;          // row within 16-row chunk
    const int lk = (l & 3) * 8;       // k element offset

    for (int ks = 0; ks < 16; ++ks) {
        const int k0 = ks * 32;
        __syncthreads();
#pragma unroll
        for (int p = 0; p < 2; ++p) {
            const int c = w * 2 + p;
            const int ar = c * 16 + lrow;
            GLL16(A + (row0 + ar) * 512 + k0 + lk, &As[c * 512]);
            GLL16(W + (long)(col0 + ar) * 512 + k0 + lk, &Bs[c * 512]);
        }
        __syncthreads();
        bf16x8 af[4], bfr[4];
#pragma unroll
        for (int mi = 0; mi < 4; ++mi)
            af[mi] = lds8(&As[(wr * 64 + mi * 16 + (l & 15)) * 32 + (l >> 4) * 8]);
#pragma unroll
        for (int nj = 0; nj < 4; ++nj)
            bfr[nj] = lds8(&Bs[(wc * 64 + nj * 16 + (l & 15)) * 32 + (l >> 4) * 8]);
#pragma unroll
        for (int mi = 0; mi < 4; ++mi)
#pragma unroll
            for (int nj = 0; nj < 4; ++nj)
                acc[mi][nj] = MFMA16(af[mi], bfr[nj], acc[mi][nj]);
    }
#pragma unroll
    for (int mi = 0; mi < 4; ++mi) {
        const long rb = row0 + wr * 64 + mi * 16 + (l >> 4) * 4;
#pragma unroll
        for (int nj = 0; nj < 4; ++nj) {
            const int cg = col0 + wc * 64 + nj * 16 + (l & 15);
            const float bv = bias[cg];
#pragma unroll
            for (int q = 0; q < 4; ++q)
                O[(rb + q) * Ntot + cg] = f2bf(geluf(acc[mi][nj][q] + bv));
        }
    }
}

// ---------------- K4: out = gelu(h @ Wo^T + b_out + b + (h.v/512).u^T/8) --------
// A-source: k<256 -> h_pass[b,k]; k>=256 -> gy[b] (ave half never materialized).
// z rides the K-loop (2 MFMA/wave/step vs v^T/512 in LDS); lora = one extra
// zero-padded MFMA K-step from z (LDS) x u/8 (registers).
__launch_bounds__(256)
__global__ void gemm_out(const unsigned short* __restrict__ Hp,  // [65536][256]
                         const unsigned short* __restrict__ Gy,  // [8192][256]
                         const unsigned short* __restrict__ Wo,  // [512][512]
                         const float* __restrict__ bo,           // [512]
                         const float* __restrict__ bb,           // [16][512]
                         const float* __restrict__ u,            // [128][512][8]
                         const float* __restrict__ v,            // [128][512][8]
                         float* __restrict__ Out) {               // [65536][512]
    __shared__ __align__(16) unsigned short As[4096];
    __shared__ __align__(16) unsigned short Bs[4096];
    __shared__ __align__(16) unsigned short Vt[16 * 528];  // [r(16, pad>=8 zero)][i 512 (+16 pad)]
    __shared__ __align__(16) unsigned short Zs[4096];      // [128][32] zero-padded z
    const int tid = threadIdx.x;
    const int w = tid >> 6, l = tid & 63;
    const int wr = w >> 1, wc = w & 1;
    const int mt = blockIdx.x;           // 0..511
    const int nt = blockIdx.y;           // 0..3
    const long row0 = (long)mt * 128;
    const int bk = mt >> 2;
    const int bi = bk >> 3;
    const int f0 = (mt & 3) * 128;
    const int col0 = nt * 128;

    // zero Vt + Zs, then fill Vt rows 0..7 with v[b,k,i,r]/512 transposed
    {
        ushort8 zz = {0, 0, 0, 0, 0, 0, 0, 0};
        for (int i = tid; i < (16 * 528) / 8; i += 256) *(ushort8*)&Vt[i * 8] = zz;
        *(ushort8*)&Zs[tid * 16] = zz;
        *(ushort8*)&Zs[tid * 16 + 8] = zz;
        __syncthreads();
        const float* vp = v + (long)bk * 4096;
#pragma unroll
        for (int p = 0; p < 4; ++p) {
            float4_t vv = *(const float4_t*)(vp + tid * 16 + p * 4);
#pragma unroll
            for (int j = 0; j < 4; ++j) {
                int flat = tid * 16 + p * 4 + j;
                Vt[(flat & 7) * 528 + (flat >> 3)] = f2bf(vv[j] * (1.0f / 512.0f));
            }
        }
    }

    f32x4 acc[4][4];
    f32x4 zacc[2];
    const f32x4 z4 = {0.f, 0.f, 0.f, 0.f};
#pragma unroll
    for (int i = 0; i < 4; ++i)
#pragma unroll
        for (int j = 0; j < 4; ++j) acc[i][j] = z4;
    zacc[0] = z4; zacc[1] = z4;

    const int lrow = l >> 2;
    const int lk = (l & 3) * 8;

    for (int ks = 0; ks < 16; ++ks) {
        const int k0 = ks * 32;
        __syncthreads();
#pragma unroll
        for (int p = 0; p < 2; ++p) {
            const int c = w * 2 + p;
            const int ar = c * 16 + lrow;
            const unsigned short* ga;
            if (k0 < 256)
                ga = Hp + (row0 + ar) * 256 + k0 + lk;
            else
                ga = Gy + (long)(bi * 512 + f0 + ar) * 256 + (k0 - 256) + lk;
            GLL16(ga, &As[c * 512]);
            GLL16(Wo + (long)(col0 + ar) * 512 + k0 + lk, &Bs[c * 512]);
        }
        __syncthreads();
        bf16x8 af[4], bfr[4];
#pragma unroll
        for (int mi = 0; mi < 4; ++mi)
            af[mi] = lds8(&As[(wr * 64 + mi * 16 + (l & 15)) * 32 + (l >> 4) * 8]);
#pragma unroll
        for (int nj = 0; nj < 4; ++nj)
            bfr[nj] = lds8(&Bs[(wc * 64 + nj * 16 + (l & 15)) * 32 + (l >> 4) * 8]);
#pragma unroll
        for (int mi = 0; mi < 4; ++mi)
#pragma unroll
            for (int nj = 0; nj < 4; ++nj)
                acc[mi][nj] = MFMA16(af[mi], bfr[nj], acc[mi][nj]);
        // z = h . v/512 : wave w owns 32 rows (frags 2w, 2w+1)
        bf16x8 bv = lds8(&Vt[(l & 15) * 528 + k0 + (l >> 4) * 8]);
#pragma unroll
        for (int q = 0; q < 2; ++q) {
            bf16x8 az = lds8(&As[((w * 2 + q) * 16 + (l & 15)) * 32 + (l >> 4) * 8]);
            zacc[q] = MFMA16(az, bv, zacc[q]);
        }
    }

    // park z in LDS (cols 8..31 stay zero), then lora as one padded MFMA step
#pragma unroll
    for (int q = 0; q < 2; ++q) {
        const int fr = w * 2 + q;
#pragma unroll
        for (int reg = 0; reg < 4; ++reg)
            Zs[(fr * 16 + (l >> 4) * 4 + reg) * 32 + (l & 15)] = f2bf(zacc[q][reg]);
    }
    __syncthreads();

    const float* up = u + (long)bk * 4096;
#pragma unroll
    for (int nj = 0; nj < 4; ++nj) {
        const int og = col0 + wc * 64 + nj * 16 + (l & 15);
        ushort8 ubits = {0, 0, 0, 0, 0, 0, 0, 0};
        if ((l >> 4) == 0) {
            float4_t u0 = *(const float4_t*)(up + og * 8);
            float4_t u1 = *(const float4_t*)(up + og * 8 + 4);
            ubits[0] = f2bf(u0[0] * 0.125f); ubits[1] = f2bf(u0[1] * 0.125f);
            ubits[2] = f2bf(u0[2] * 0.125f); ubits[3] = f2bf(u0[3] * 0.125f);
            ubits[4] = f2bf(u1[0] * 0.125f); ubits[5] = f2bf(u1[1] * 0.125f);
            ubits[6] = f2bf(u1[2] * 0.125f); ubits[7] = f2bf(u1[3] * 0.125f);
        }
        bf16x8 ub = __builtin_bit_cast(bf16x8, ubits);
#pragma unroll
        for (int mi = 0; mi < 4; ++mi) {
            bf16x8 az = lds8(&Zs[(wr * 64 + mi * 16 + (l & 15)) * 32 + (l >> 4) * 8]);
            acc[mi][nj] = MFMA16(az, ub, acc[mi][nj]);
        }
    }

#pragma unroll
    for (int mi = 0; mi < 4; ++mi) {
        const long rb = row0 + wr * 64 + mi * 16 + (l >> 4) * 4;
#pragma unroll
        for (int nj = 0; nj < 4; ++nj) {
            const int og = col0 + wc * 64 + nj * 16 + (l & 15);
            const float badd = bo[og] + bb[bi * 512 + og];
#pragma unroll
            for (int q = 0; q < 4; ++q)
                Out[(rb + q) * 512 + og] = geluf(acc[mi][nj][q] + badd);
        }
    }
}

extern "C" void kernel_launch(void* const* d_in, const int* in_sizes, int n_in,
                              void* d_out, int out_size, void* d_ws, size_t ws_size,
                              hipStream_t stream) {
    const float* x  = (const float*)d_in[0];
    const float* u  = (const float*)d_in[1];
    const float* v  = (const float*)d_in[2];
    const float* bb = (const float*)d_in[3];
    const float* Wp = (const float*)d_in[4];
    const float* bp = (const float*)d_in[5];
    const float* Wa = (const float*)d_in[6];
    const float* ba = (const float*)d_in[7];
    const float* Wo = (const float*)d_in[8];
    const float* bo = (const float*)d_in[9];
    float* out = (float*)d_out;

    char* ws = (char*)d_ws;
    unsigned short* xb  = (unsigned short*)(ws + 0);          //  67108864 B [65536][512]
    unsigned short* xm  = (unsigned short*)(ws + 67108864);   //   8388608 B [8192][512]
    unsigned short* gy  = (unsigned short*)(ws + 75497472);   //   4194304 B [8192][256]
    unsigned short* hp  = (unsigned short*)(ws + 79691776);   //  33554432 B [65536][256]
    unsigned short* Wpb = (unsigned short*)(ws + 113246208);  //    262144 B
    unsigned short* Wab = (unsigned short*)(ws + 113508352);  //    262144 B
    unsigned short* Wob = (unsigned short*)(ws + 113770496);  //    524288 B (total 114294784)

    cvt_w<<<128, 256, 0, stream>>>(Wp, Wpb);
    cvt_w<<<128, 256, 0, stream>>>(Wa, Wab);
    cvt_w<<<256, 256, 0, stream>>>(Wo, Wob);
    mean_cvt<<<4096, 256, 0, stream>>>(x, xb, xm);
    // gy = gelu(xm @ W_ave^T + b_ave)      M=8192,  N=256
    gemm_gelu<<<dim3(64, 2), 256, 0, stream>>>(xm, Wab, ba, gy, 256);
    // h_pass = gelu(x @ W_pass^T + b_pass) M=65536, N=256
    gemm_gelu<<<dim3(512, 2), 256, 0, stream>>>(xb, Wpb, bp, hp, 256);
    // out = gelu(h @ Wo^T + b_out + b + lora)
    gemm_out<<<dim3(512, 4), 256, 0, stream>>>(hp, gy, Wob, bo, bb, u, v, out);
}

// Round 2
// 178.264 us; speedup vs baseline: 1.0647x; 1.0647x over previous
//
#include <hip/hip_runtime.h>
#include <stdint.h>

// Problem constants: B=16, K=8, F=512, INCH=512, OUTCH=512, R=8
// rows M = B*K*F = 65536; "bk" index = b*8+k (128 slices of 512 rows)

typedef __attribute__((ext_vector_type(8))) __bf16 bf16x8;
typedef __attribute__((ext_vector_type(4))) float f32x4;
typedef __attribute__((ext_vector_type(8))) unsigned short ushort8;
typedef __attribute__((ext_vector_type(4))) unsigned short ushort4_t;
typedef __attribute__((ext_vector_type(4))) float float4_t;

#define MFMA16(a, b, c) __builtin_amdgcn_mfma_f32_16x16x32_bf16((a), (b), (c), 0, 0, 0)
#define GLL16(g, l)                                                                   \
    __builtin_amdgcn_global_load_lds((const __attribute__((address_space(1))) void*)(g), \
                                     (__attribute__((address_space(3))) void*)(l), 16, 0, 0)

__device__ inline unsigned short f2bf(float f) {
    union { float fv; unsigned u; } un; un.fv = f;
    unsigned u = un.u;
    u += 0x7FFFu + ((u >> 16) & 1u);   // RNE
    return (unsigned short)(u >> 16);
}

// fast gelu: x * sigmoid(2*0.7978845608*(x + 0.044715 x^3)); max |err| vs exact ~2.5e-4
__device__ inline float geluf(float x) {
    float x2 = x * x;
    float inner = x + 0.044715f * x * x2;
    float e = __expf(-1.5957691216057308f * inner);
    return x * __builtin_amdgcn_rcpf(1.0f + e);
}

__device__ inline bf16x8 lds8(const unsigned short* p) {
    return __builtin_bit_cast(bf16x8, *(const ushort8*)p);
}

// ---------------- K0: all three weight mats fp32 -> bf16 in one launch ----------
__global__ void cvt_all(const float* __restrict__ a, const float* __restrict__ b,
                        const float* __restrict__ c, unsigned short* __restrict__ oa,
                        unsigned short* __restrict__ ob, unsigned short* __restrict__ oc) {
    int bid = blockIdx.x;                // 512 blocks: 128 Wp, 128 Wa, 256 Wo
    const float* s; unsigned short* d; int off;
    if (bid < 128) { s = a; d = oa; off = bid; }
    else if (bid < 256) { s = b; d = ob; off = bid - 128; }
    else { s = c; d = oc; off = bid - 256; }
    int i = off * 256 + threadIdx.x;     // float4 index
    float4_t v = *(const float4_t*)(s + (size_t)i * 4);
    ushort4_t r;
    r[0] = f2bf(v[0]); r[1] = f2bf(v[1]); r[2] = f2bf(v[2]); r[3] = f2bf(v[3]);
    *(ushort4_t*)(d + (size_t)i * 4) = r;
}

// ---------------- K1: mean over K (fp32) + x -> bf16.  grid 4096 x 256 ----------
__global__ void mean_cvt(const float* __restrict__ x,
                         unsigned short* __restrict__ xb,
                         unsigned short* __restrict__ xm) {
    int gid = blockIdx.x * 256 + threadIdx.x;   // B*F*128 = 1048576 threads
    int c  = gid & 127;          // float4 column
    int bf = gid >> 7;           // 0..8191
    int b  = bf >> 9;
    int f  = bf & 511;
    float4_t s = {0.f, 0.f, 0.f, 0.f};
#pragma unroll
    for (int k = 0; k < 8; ++k) {
        long row = (long)(b * 8 + k) * 512 + f;
        float4_t v = *(const float4_t*)(x + row * 512 + c * 4);
        s += v;
        ushort4_t t;
        t[0] = f2bf(v[0]); t[1] = f2bf(v[1]); t[2] = f2bf(v[2]); t[3] = f2bf(v[3]);
        *(ushort4_t*)(xb + row * 512 + c * 4) = t;
    }
    ushort4_t t;
    t[0] = f2bf(s[0] * 0.125f); t[1] = f2bf(s[1] * 0.125f);
    t[2] = f2bf(s[2] * 0.125f); t[3] = f2bf(s[3] * 0.125f);
    *(ushort4_t*)(xm + (long)bf * 512 + c * 4) = t;
}

// ---------------- K2/K3: O[M][256] = gelu(A[M][512] @ W[256][512]^T + bias) bf16
// 128x128 tile, BK=32, 4 waves (2x2), m97 structure, XCD-chunked 1-D grid.
__launch_bounds__(256)
__global__ void gemm_gelu(const unsigned short* __restrict__ A,
                          const unsigned short* __restrict__ W,
                          const float* __restrict__ bias,
                          unsigned short* __restrict__ O,
                          int chunk) {                       // chunk = nwg/8
    __shared__ __align__(16) unsigned short As[4096];  // [128 rows][32 k]
    __shared__ __align__(16) unsigned short Bs[4096];  // [128 cols][32 k]
    const int tid = threadIdx.x;
    const int w = tid >> 6, l = tid & 63;
    const int wr = w >> 1, wc = w & 1;
    const int bid = blockIdx.x;
    const int work = (bid & 7) * chunk + (bid >> 3);   // bijective (nwg % 8 == 0)
    const int nt = work & 1;                           // nt fastest: same-XCD blocks share A panel
    const int mt = work >> 1;
    const long row0 = (long)mt * 128;
    const int  col0 = nt * 128;

    f32x4 acc[4][4];
    const f32x4 z4 = {0.f, 0.f, 0.f, 0.f};
#pragma unroll
    for (int i = 0; i < 4; ++i)
#pragma unroll
        for (int j = 0; j < 4; ++j) acc[i][j] = z4;

    const int lrow = l >> 2;          // row within 16-row chunk
    const int lk = (l & 3) * 8;       // k element offset

    for (int ks = 0; ks < 16; ++ks) {
        const int k0 = ks * 32;
        __syncthreads();
#pragma unroll
        for (int p = 0; p < 2; ++p) {
            const int c = w * 2 + p;
            const int ar = c * 16 + lrow;
            GLL16(A + (row0 + ar) * 512 + k0 + lk, &As[c * 512]);
            GLL16(W + (long)(col0 + ar) * 512 + k0 + lk, &Bs[c * 512]);
        }
        __syncthreads();
        bf16x8 af[4], bfr[4];
#pragma unroll
        for (int mi = 0; mi < 4; ++mi)
            af[mi] = lds8(&As[(wr * 64 + mi * 16 + (l & 15)) * 32 + (l >> 4) * 8]);
#pragma unroll
        for (int nj = 0; nj < 4; ++nj)
            bfr[nj] = lds8(&Bs[(wc * 64 + nj * 16 + (l & 15)) * 32 + (l >> 4) * 8]);
#pragma unroll
        for (int mi = 0; mi < 4; ++mi)
#pragma unroll
            for (int nj = 0; nj < 4; ++nj)
                acc[mi][nj] = MFMA16(af[mi], bfr[nj], acc[mi][nj]);
    }
#pragma unroll
    for (int mi = 0; mi < 4; ++mi) {
        const long rb = row0 + wr * 64 + mi * 16 + (l >> 4) * 4;
#pragma unroll
        for (int nj = 0; nj < 4; ++nj) {
            const int cg = col0 + wc * 64 + nj * 16 + (l & 15);
            const float bv = bias[cg];
#pragma unroll
            for (int q = 0; q < 4; ++q)
                O[(rb + q) * 256 + cg] = f2bf(geluf(acc[mi][nj][q] + bv));
        }
    }
}

// ---------------- K4: z[row][r] = (h . v)/512 via MFMA, h = [hp | gy] ------------
__launch_bounds__(256)
__global__ void zcalc(const unsigned short* __restrict__ Hp,   // [65536][256]
                      const unsigned short* __restrict__ Gy,   // [8192][256]
                      const float* __restrict__ v,             // [128][512][8]
                      unsigned short* __restrict__ zb) {       // [65536][8] bf16
    __shared__ __align__(16) unsigned short As[4096];          // [128][32]
    __shared__ __align__(16) unsigned short Vt[16 * 536];      // [r 16 (8..15 zero)][i 512]
    const int tid = threadIdx.x;
    const int w = tid >> 6, l = tid & 63;
    const int mt = blockIdx.x;           // 0..511
    const long row0 = (long)mt * 128;
    const int bk = mt >> 2;
    const int bi = bk >> 3;
    const int f0 = (mt & 3) * 128;
    {
        ushort8 zz = {0, 0, 0, 0, 0, 0, 0, 0};
        for (int i = tid; i < (16 * 536) / 8; i += 256) *(ushort8*)&Vt[i * 8] = zz;
        __syncthreads();
        const float* vp = v + (long)bk * 4096;
#pragma unroll
        for (int p = 0; p < 4; ++p) {
            float4_t vv = *(const float4_t*)(vp + tid * 16 + p * 4);
#pragma unroll
            for (int j = 0; j < 4; ++j) {
                int flat = tid * 16 + p * 4 + j;   // = i*8 + r
                Vt[(flat & 7) * 536 + (flat >> 3)] = f2bf(vv[j] * (1.0f / 512.0f));
            }
        }
    }
    f32x4 zacc[2];
    const f32x4 z4 = {0.f, 0.f, 0.f, 0.f};
    zacc[0] = z4; zacc[1] = z4;
    const int lrow = l >> 2;
    const int lk = (l & 3) * 8;
    for (int ks = 0; ks < 16; ++ks) {
        const int k0 = ks * 32;
        __syncthreads();
#pragma unroll
        for (int p = 0; p < 2; ++p) {
            const int c = w * 2 + p;
            const int ar = c * 16 + lrow;
            const unsigned short* ga = (k0 < 256)
                ? Hp + (row0 + ar) * 256 + k0 + lk
                : Gy + (long)(bi * 512 + f0 + ar) * 256 + (k0 - 256) + lk;
            GLL16(ga, &As[c * 512]);
        }
        __syncthreads();
        bf16x8 bv = lds8(&Vt[(l & 15) * 536 + k0 + (l >> 4) * 8]);
#pragma unroll
        for (int q = 0; q < 2; ++q) {
            bf16x8 az = lds8(&As[((w * 2 + q) * 16 + (l & 15)) * 32 + (l >> 4) * 8]);
            zacc[q] = MFMA16(az, bv, zacc[q]);
        }
    }
    if ((l & 15) < 8) {
#pragma unroll
        for (int q = 0; q < 2; ++q) {
            const int fr = w * 2 + q;
#pragma unroll
            for (int reg = 0; reg < 4; ++reg) {
                long r = row0 + fr * 16 + (l >> 4) * 4 + reg;
                zb[r * 8 + (l & 15)] = f2bf(zacc[q][reg]);
            }
        }
    }
}

// ---------------- K5: out = gelu(h @ Wo^T + b_out + b + z.u^T/8) ----------------
// Pure m97 GEMM; lora via one zero-padded MFMA K-step (Zs aliases As).
__launch_bounds__(256)
__global__ void gemm_out(const unsigned short* __restrict__ Hp,  // [65536][256]
                         const unsigned short* __restrict__ Gy,  // [8192][256]
                         const unsigned short* __restrict__ Wo,  // [512][512]
                         const float* __restrict__ bo,           // [512]
                         const float* __restrict__ bb,           // [16][512]
                         const float* __restrict__ u,            // [128][512][8]
                         const unsigned short* __restrict__ zb,  // [65536][8]
                         float* __restrict__ Out) {               // [65536][512]
    __shared__ __align__(16) unsigned short As[4096];
    __shared__ __align__(16) unsigned short Bs[4096];
    const int tid = threadIdx.x;
    const int w = tid >> 6, l = tid & 63;
    const int wr = w >> 1, wc = w & 1;
    const int bid = blockIdx.x;                    // 0..2047
    const int work = (bid & 7) * 256 + (bid >> 3); // XCD-chunked bijection
    const int nt = work & 3;                       // nt fastest: same-XCD shares hp panel
    const int mt = work >> 2;
    const long row0 = (long)mt * 128;
    const int bk = mt >> 2;
    const int bi = bk >> 3;
    const int f0 = (mt & 3) * 128;
    const int col0 = nt * 128;

    f32x4 acc[4][4];
    const f32x4 z4 = {0.f, 0.f, 0.f, 0.f};
#pragma unroll
    for (int i = 0; i < 4; ++i)
#pragma unroll
        for (int j = 0; j < 4; ++j) acc[i][j] = z4;

    const int lrow = l >> 2;
    const int lk = (l & 3) * 8;

    for (int ks = 0; ks < 16; ++ks) {
        const int k0 = ks * 32;
        __syncthreads();
#pragma unroll
        for (int p = 0; p < 2; ++p) {
            const int c = w * 2 + p;
            const int ar = c * 16 + lrow;
            const unsigned short* ga = (k0 < 256)
                ? Hp + (row0 + ar) * 256 + k0 + lk
                : Gy + (long)(bi * 512 + f0 + ar) * 256 + (k0 - 256) + lk;
            GLL16(ga, &As[c * 512]);
            GLL16(Wo + (long)(col0 + ar) * 512 + k0 + lk, &Bs[c * 512]);
        }
        __syncthreads();
        bf16x8 af[4], bfr[4];
#pragma unroll
        for (int mi = 0; mi < 4; ++mi)
            af[mi] = lds8(&As[(wr * 64 + mi * 16 + (l & 15)) * 32 + (l >> 4) * 8]);
#pragma unroll
        for (int nj = 0; nj < 4; ++nj)
            bfr[nj] = lds8(&Bs[(wc * 64 + nj * 16 + (l & 15)) * 32 + (l >> 4) * 8]);
#pragma unroll
        for (int mi = 0; mi < 4; ++mi)
#pragma unroll
            for (int nj = 0; nj < 4; ++nj)
                acc[mi][nj] = MFMA16(af[mi], bfr[nj], acc[mi][nj]);
    }

    // park z (zero-padded to k=32) into As, then lora as one padded MFMA step
    __syncthreads();
    {
        ushort8 zz = {0, 0, 0, 0, 0, 0, 0, 0};
        const int row = tid >> 1;
        if ((tid & 1) == 0) {
            *(ushort8*)&As[row * 32]     = *(const ushort8*)&zb[(row0 + row) * 8];
            *(ushort8*)&As[row * 32 + 8] = zz;
        } else {
            *(ushort8*)&As[row * 32 + 16] = zz;
            *(ushort8*)&As[row * 32 + 24] = zz;
        }
    }
    __syncthreads();

    const float* up = u + (long)bk * 4096;
#pragma unroll
    for (int nj = 0; nj < 4; ++nj) {
        const int og = col0 + wc * 64 + nj * 16 + (l & 15);
        ushort8 ubits = {0, 0, 0, 0, 0, 0, 0, 0};
        if ((l >> 4) == 0) {
            float4_t u0 = *(const float4_t*)(up + og * 8);
            float4_t u1 = *(const float4_t*)(up + og * 8 + 4);
            ubits[0] = f2bf(u0[0] * 0.125f); ubits[1] = f2bf(u0[1] * 0.125f);
            ubits[2] = f2bf(u0[2] * 0.125f); ubits[3] = f2bf(u0[3] * 0.125f);
            ubits[4] = f2bf(u1[0] * 0.125f); ubits[5] = f2bf(u1[1] * 0.125f);
            ubits[6] = f2bf(u1[2] * 0.125f); ubits[7] = f2bf(u1[3] * 0.125f);
        }
        bf16x8 ub = __builtin_bit_cast(bf16x8, ubits);
#pragma unroll
        for (int mi = 0; mi < 4; ++mi) {
            bf16x8 az = lds8(&As[(wr * 64 + mi * 16 + (l & 15)) * 32 + (l >> 4) * 8]);
            acc[mi][nj] = MFMA16(az, ub, acc[mi][nj]);
        }
    }

#pragma unroll
    for (int mi = 0; mi < 4; ++mi) {
        const long rb = row0 + wr * 64 + mi * 16 + (l >> 4) * 4;
#pragma unroll
        for (int nj = 0; nj < 4; ++nj) {
            const int og = col0 + wc * 64 + nj * 16 + (l & 15);
            const float badd = bo[og] + bb[bi * 512 + og];
#pragma unroll
            for (int q = 0; q < 4; ++q)
                Out[(rb + q) * 512 + og] = geluf(acc[mi][nj][q] + badd);
        }
    }
}

extern "C" void kernel_launch(void* const* d_in, const int* in_sizes, int n_in,
                              void* d_out, int out_size, void* d_ws, size_t ws_size,
                              hipStream_t stream) {
    const float* x  = (const float*)d_in[0];
    const float* u  = (const float*)d_in[1];
    const float* v  = (const float*)d_in[2];
    const float* bb = (const float*)d_in[3];
    const float* Wp = (const float*)d_in[4];
    const float* bp = (const float*)d_in[5];
    const float* Wa = (const float*)d_in[6];
    const float* ba = (const float*)d_in[7];
    const float* Wo = (const float*)d_in[8];
    const float* bo = (const float*)d_in[9];
    float* out = (float*)d_out;

    char* ws = (char*)d_ws;
    unsigned short* xb  = (unsigned short*)(ws + 0);          //  67108864 B [65536][512]
    unsigned short* zb  = (unsigned short*)(ws + 0);          //   1048576 B [65536][8] (reuses dead xb)
    unsigned short* xm  = (unsigned short*)(ws + 67108864);   //   8388608 B [8192][512]
    unsigned short* gy  = (unsigned short*)(ws + 75497472);   //   4194304 B [8192][256]
    unsigned short* hp  = (unsigned short*)(ws + 79691776);   //  33554432 B [65536][256]
    unsigned short* Wpb = (unsigned short*)(ws + 113246208);  //    262144 B
    unsigned short* Wab = (unsigned short*)(ws + 113508352);  //    262144 B
    unsigned short* Wob = (unsigned short*)(ws + 113770496);  //    524288 B (total 114294784)

    cvt_all<<<512, 256, 0, stream>>>(Wp, Wa, Wo, Wpb, Wab, Wob);
    mean_cvt<<<4096, 256, 0, stream>>>(x, xb, xm);
    // gy = gelu(xm @ W_ave^T + b_ave)      M=8192,  N=256, 128 blocks
    gemm_gelu<<<128, 256, 0, stream>>>(xm, Wab, ba, gy, 16);
    // h_pass = gelu(x @ W_pass^T + b_pass) M=65536, N=256, 1024 blocks (xb dead after this)
    gemm_gelu<<<1024, 256, 0, stream>>>(xb, Wpb, bp, hp, 128);
    // z = (h . v)/512
    zcalc<<<512, 256, 0, stream>>>(hp, gy, v, zb);
    // out = gelu(h @ Wo^T + b_out + b + lora)
    gemm_out<<<2048, 256, 0, stream>>>(hp, gy, Wob, bo, bb, u, zb, out);
}